// Round 11
// baseline (2833.688 us; speedup 1.0000x reference)
//
#include <hip/hip_runtime.h>

// TimeframeEncoder R23 == R22 resubmitted unchanged (R10 bench died with
// "MI355X container failed twice" -- infra error, no kernel signal; audit
// of the C-only diff found no hang/fault path: prefetch targets stay within
// the published chunk, all vmcnt waits are unconditionally satisfiable,
// barriers are uniform across all 512 threads).
//
// R22 rationale: C is the pacer with ZERO slack (R21 probe: +1.4k cy/step
// dependent-MFMA chain appeared in the pace at full magnitude; B has
// >=1.8k slack per R19; A drain not critical per R20). C's largest
// identifiable serial stall: the blocking sc0sc1 ld_part6 (vmcnt(0)) at
// every step top -- a coherence-point round trip on the serial recurrence.
// Fix (C only): issue s+1's 6 loads at step top (no wait); mid barrier ->
// lgkm-only lbar (R20-proven); end-of-step __syncthreads drains the
// prefetch after a full step (~3k cy) of overlap. C has no in-step global
// stores => no write-combining risk. A/B byte-identical to R20.

#define SEQL 512
#define CH 8
#define NCH 64
#define DEPTH 4

#define RB0  1310720u                   // rings base (weights end 1,277,952)
#define GSTR 1048576u                   // per group: 4x64KB h0 + 4x192KB partials
#define CTRB (RB0 + 16u * GSTR)         // counters: 16 groups x 64 B

typedef __bf16 bf16x8 __attribute__((ext_vector_type(8)));
typedef float f32x4 __attribute__((ext_vector_type(4)));
typedef unsigned int u32x4 __attribute__((ext_vector_type(4)));
typedef unsigned long long u64;

__device__ __forceinline__ unsigned short f2bf(float f) {
  unsigned int u = __builtin_bit_cast(unsigned int, f);
  u += 0x7fffu + ((u >> 16) & 1u);
  return (unsigned short)(u >> 16);
}
__device__ __forceinline__ float bf2f(unsigned short u) {
  unsigned int v = ((unsigned int)u) << 16;
  return __builtin_bit_cast(float, v);
}
__device__ __forceinline__ float sigm(float x) { return 1.0f / (1.0f + __expf(-x)); }
__device__ __forceinline__ float tanh_(float x) { return 1.0f - 2.0f / (__expf(2.0f * x) + 1.0f); }
__device__ __forceinline__ float sanit(float v) {
  if (!(v == v)) return 0.f;
  if (isinf(v)) return v > 0.f ? 10.f : -10.f;
  return v;
}

// agent-coherent stores (fire-and-forget; proven correct R8/R11)
__device__ __forceinline__ void st8(u64* p, u64 v) {
  __hip_atomic_store(p, v, __ATOMIC_RELAXED, __HIP_MEMORY_SCOPE_AGENT);
}
// 16B device-coherent store (same sc0 sc1 encoding, wider; R16/R20-verified)
__device__ __forceinline__ void st16(void* p, u32x4 v) {
  asm volatile("global_store_dwordx4 %0, %1, off sc0 sc1" :: "v"(p), "v"(v) : "memory");
}

// lgkm-only barrier: orders LDS without draining outstanding global ops.
__device__ __forceinline__ void lbar() {
  asm volatile("s_waitcnt lgkmcnt(0)" ::: "memory");
  __builtin_amdgcn_sched_barrier(0);
  __builtin_amdgcn_s_barrier();
  __builtin_amdgcn_sched_barrier(0);
}

// ---- batched device-coherent load blocks ----
__device__ __forceinline__ void ld_frame8(const unsigned short* base, int lane, u32x4* c) {
  const char* p0 = (const char*)base + lane * 16;
  const char* p4 = p0 + 4096;
  asm volatile(
      "global_load_dwordx4 %0, %8, off sc0 sc1\n\t"
      "global_load_dwordx4 %1, %8, off offset:1024 sc0 sc1\n\t"
      "global_load_dwordx4 %2, %8, off offset:2048 sc0 sc1\n\t"
      "global_load_dwordx4 %3, %8, off offset:3072 sc0 sc1\n\t"
      "global_load_dwordx4 %4, %9, off sc0 sc1\n\t"
      "global_load_dwordx4 %5, %9, off offset:1024 sc0 sc1\n\t"
      "global_load_dwordx4 %6, %9, off offset:2048 sc0 sc1\n\t"
      "global_load_dwordx4 %7, %9, off offset:3072 sc0 sc1\n\t"
      "s_waitcnt vmcnt(0)"
      : "=&v"(c[0]), "=&v"(c[1]), "=&v"(c[2]), "=&v"(c[3]),
        "=&v"(c[4]), "=&v"(c[5]), "=&v"(c[6]), "=&v"(c[7])
      : "v"(p0), "v"(p4)
      : "memory");
}
__device__ __forceinline__ void ld_part6(const unsigned short* pf, int wave, int lane,
                                         u64* z, u64* r, u64* c) {
  const char* p0 = (const char*)pf + ((2 * wave) * 64 + lane) * 8;
  const char* p1 = p0 + 8192;
  const char* p2 = p0 + 16384;
  asm volatile(
      "global_load_dwordx2 %0, %6, off sc0 sc1\n\t"
      "global_load_dwordx2 %1, %6, off offset:512 sc0 sc1\n\t"
      "global_load_dwordx2 %2, %7, off sc0 sc1\n\t"
      "global_load_dwordx2 %3, %7, off offset:512 sc0 sc1\n\t"
      "global_load_dwordx2 %4, %8, off sc0 sc1\n\t"
      "global_load_dwordx2 %5, %8, off offset:512 sc0 sc1\n\t"
      "s_waitcnt vmcnt(0)"
      : "=&v"(z[0]), "=&v"(z[1]), "=&v"(r[0]), "=&v"(r[1]),
        "=&v"(c[0]), "=&v"(c[1])
      : "v"(p0), "v"(p1), "v"(p2)
      : "memory");
}
// issue-only variant (prefetch): no waitcnt inside.
__device__ __forceinline__ void ld_part6_issue(const unsigned short* pf, int wave, int lane,
                                               u64* z, u64* r, u64* c) {
  const char* p0 = (const char*)pf + ((2 * wave) * 64 + lane) * 8;
  const char* p1 = p0 + 8192;
  const char* p2 = p0 + 16384;
  asm volatile(
      "global_load_dwordx2 %0, %6, off sc0 sc1\n\t"
      "global_load_dwordx2 %1, %6, off offset:512 sc0 sc1\n\t"
      "global_load_dwordx2 %2, %7, off sc0 sc1\n\t"
      "global_load_dwordx2 %3, %7, off offset:512 sc0 sc1\n\t"
      "global_load_dwordx2 %4, %8, off sc0 sc1\n\t"
      "global_load_dwordx2 %5, %8, off offset:512 sc0 sc1"
      : "=&v"(z[0]), "=&v"(z[1]), "=&v"(r[0]), "=&v"(r[1]),
        "=&v"(c[0]), "=&v"(c[1])
      : "v"(p0), "v"(p1), "v"(p2)
      : "memory");
}
// reg-tie wait before consuming prefetched data (free if end-of-step
// __syncthreads already drained; guards compiler reordering -- rule #18)
__device__ __forceinline__ void wait_tie6(u64* z, u64* r, u64* c) {
  asm volatile("s_waitcnt vmcnt(0)"
      : "+v"(z[0]), "+v"(z[1]), "+v"(r[0]), "+v"(r[1]), "+v"(c[0]), "+v"(c[1])
      :: "memory");
  __builtin_amdgcn_sched_barrier(0);
}

// Weight prep (layout verified R1-R11): bf16 B-fragments, tile = 512 ushort,
// lane L holds B[k=(L>>4)*8+j][n=L&15]. Wz0p tiles [0,320) (nt<32,kt<10);
// Wc0p base 320 (nt<16,kt<10); Wz1p base 480 (nt<32,kt<16); Wc1p base 992.
__global__ __launch_bounds__(256) void prep_weights(
    const float* __restrict__ Wz0, const float* __restrict__ Wc0,
    const float* __restrict__ Wz1, const float* __restrict__ Wc1,
    unsigned short* __restrict__ ws) {
  int idx = blockIdx.x * 256 + threadIdx.x;  // 638976 threads
  const float* W;
  int stride, KT, base;
  if (idx < 163840)      { W = Wz0; stride = 768; KT = 10; base = 0; }
  else if (idx < 245760) { W = Wc0; stride = 256; KT = 10; base = 163840; idx -= 163840; }
  else if (idx < 507904) { W = Wz1; stride = 768; KT = 16; base = 245760; idx -= 245760; }
  else                   { W = Wc1; stride = 256; KT = 16; base = 507904; idx -= 507904; }
  int tile = idx >> 9;
  int t = idx & 511;
  int nt = tile / KT;
  int kt = tile - nt * KT;
  int n15 = t & 15;
  int klocal = t >> 4;
  int k = (kt << 5) + klocal;
  int n = (nt << 4) + n15;
  int lane = ((klocal >> 3) << 4) | n15;
  int j = klocal & 7;
  ws[base + (tile << 9) + (lane << 3) + j] = f2bf(W[k * stride + n]);
}

__device__ __forceinline__ void waitge(int* p, int v, int tid) {
  __syncthreads();
  if (tid == 0) {
    long it = 0;
    while (__hip_atomic_load(p, __ATOMIC_RELAXED, __HIP_MEMORY_SCOPE_AGENT) < v) {
      __builtin_amdgcn_s_sleep(1);
      if (++it > (1L << 24)) break;  // valve against true deadlock
    }
  }
  __syncthreads();
}
__device__ __forceinline__ void publish(int* p, int v, int tid) {
  asm volatile("s_waitcnt vmcnt(0)" ::: "memory");
  __syncthreads();
  if (tid == 0) __hip_atomic_store(p, v, __ATOMIC_RELAXED, __HIP_MEMORY_SCOPE_AGENT);
}

#define DLOC(c) ((((c) >> 5) << 9) + (((((c) >> 3) & 3) << 4) + (quad << 2)) * 8 + ((c) & 7))
#define MFMA(a, b, c) __builtin_amdgcn_mfma_f32_16x16x32_bf16((a), (b), (c), 0, 0, 0)

union UB  { u32x4 q; bf16x8 v; };
union UB8 { u64 q; ushort4 s; };

__global__ __launch_bounds__(512, 2) void gru_pipe(
    const float* __restrict__ x,
    const float* __restrict__ bz0, const float* __restrict__ bc0,
    const float* __restrict__ bz1, const float* __restrict__ bc1,
    const float* __restrict__ gamma, const float* __restrict__ beta,
    const unsigned short* __restrict__ wsw,
    unsigned short* __restrict__ gws,
    float* __restrict__ out) {
  __shared__ __align__(16) unsigned short lds[75776];  // 148 KB (stage A max)
  const int tid  = threadIdx.x;
  const int wave = tid >> 6;   // 0..7
  const int lane = tid & 63;
  const int l15  = lane & 15;
  const int quad = lane >> 4;
  const int stage = blockIdx.x >> 4;
  const int g     = blockIdx.x & 15;
  const int row0  = g << 4;

  const bf16x8* __restrict__ wsv = (const bf16x8*)wsw;
  unsigned short* ringh = gws + (RB0 >> 1) + (size_t)g * (GSTR >> 1);  // 4 x 32768 ushort
  unsigned short* ringp = ringh + 131072;                              // 4 x 98304 ushort
  int* ctr = (int*)((char*)gws + CTRB) + g * 16;  // [0]A_pub [1]B_pub [2]B_ack [3]C_ack

  if (stage == 0) {
    // ================= Stage A: layer0 (byte-identical to R20) =================
    unsigned short* h0f  = lds;            // 8 kt A-frag of h0
    unsigned short* rh0f = lds + 4096;
    unsigned short* xf   = lds + 8192;     // 2 bufs x 2 kt
    unsigned short* xw   = lds + 10240;    // x-part B tiles: 96 x 512 ushort
    unsigned short* cw0  = lds + 59392;    // Wc0 h-part kt 6,7: 32 tiles (32 KB)
    for (int u = tid; u < 6144; u += 512) {
      int flat = u << 3, ti = flat >> 9, q = flat & 511, srct;
      if (ti < 64) srct = (ti >> 1) * 10 + 8 + (ti & 1);
      else         srct = 320 + ((ti - 64) >> 1) * 10 + 8 + (ti & 1);
      *(uint4*)(xw + flat) = *(const uint4*)(wsw + srct * 512 + q);
    }
    for (int u = tid; u < 2048; u += 512) {  // cw0: tile ti = nt*2 + kk, kk = k-6
      int flat = u << 3, ti = flat >> 9, q = flat & 511;
      int srct = 320 + (ti >> 1) * 10 + 6 + (ti & 1);
      *(uint4*)(cw0 + flat) = *(const uint4*)(wsw + srct * 512 + q);
    }
    for (int i = tid; i < 4096; i += 512) h0f[i] = 0;

    // per-wave (j<2): z,r h-part -> AGPR (32 tiles = 128); c kt<6 -> AGPR (48)
    bf16x8 pz[2][8], pr[2][8], pc[2][6];
#pragma unroll
    for (int j = 0; j < 2; ++j) {
      const int zt = 2 * wave + j;
#pragma unroll
      for (int k = 0; k < 8; ++k) {
        pz[j][k] = wsv[(zt * 10 + k) * 64 + lane];
        pr[j][k] = wsv[((16 + zt) * 10 + k) * 64 + lane];
      }
#pragma unroll
      for (int k = 0; k < 6; ++k)
        pc[j][k] = wsv[(320 + zt * 10 + k) * 64 + lane];
    }
#pragma unroll
    for (int j = 0; j < 2; ++j) {
#pragma unroll
      for (int k = 0; k < 8; ++k)
        asm volatile("" : "+a"(pz[j][k]), "+a"(pr[j][k]));
#pragma unroll
      for (int k = 0; k < 6; ++k)
        asm volatile("" : "+a"(pc[j][k]));
    }

    float bzz[2], bzr[2], bcc[2];
    int dloc[2];
#pragma unroll
    for (int j = 0; j < 2; ++j) {
      const int col = 32 * wave + 16 * j + l15;
      bzz[j] = bz0[col]; bzr[j] = bz0[256 + col]; bcc[j] = bc0[col];
      dloc[j] = DLOC(col);
    }
    f32x4 h0s[2] = {{0,0,0,0},{0,0,0,0}};

    const int xrow = (tid >> 4) & 15, c4 = (tid & 15) << 2;
    const float* xp = x + (size_t)(row0 + xrow) * (SEQL * 64) + c4;
    const int xbase = ((c4 >> 5) << 9) + ((((c4 >> 3) & 3) << 4) + xrow) * 8 + (c4 & 7);
    if (tid < 256) {
      float4 xv = *(const float4*)xp;
      xf[xbase] = f2bf(sanit(xv.x)); xf[xbase + 1] = f2bf(sanit(xv.y));
      xf[xbase + 2] = f2bf(sanit(xv.z)); xf[xbase + 3] = f2bf(sanit(xv.w));
    }
    __syncthreads();

    for (int ch = 0; ch < NCH; ++ch) {
      if (ch >= DEPTH) waitge(ctr + 2, ch - (DEPTH - 1), tid);   // B freed this slot
      unsigned short* slot = ringh + (ch & (DEPTH - 1)) * (CH * 4096);
      for (int s = 0; s < CH; ++s) {
        const int t = (ch << 3) + s;
        if (s > 0) {  // prev step's h0 frame: one 16B coherent store/thread
          u32x4 fv = *(const u32x4*)((const char*)h0f + 16 * tid);
          st16((char*)(slot + (s - 1) * 4096) + 16 * tid, fv);
        }
        const unsigned short* xb = xf + ((t & 1) << 10);
        const bool havex = (t + 1 < SEQL) && (tid < 256);
        float4 xn;
        if (havex) xn = *(const float4*)(xp + (t + 1) * 64);

        f32x4 za[2], ra[2];
#pragma unroll
        for (int j = 0; j < 2; ++j) { za[j] = {bzz[j],bzz[j],bzz[j],bzz[j]}; ra[j] = {bzr[j],bzr[j],bzr[j],bzr[j]}; }
#pragma unroll
        for (int k = 0; k < 8; ++k) {
          bf16x8 a = *(const bf16x8*)(h0f + (k << 9) + (lane << 3));
#pragma unroll
          for (int j = 0; j < 2; ++j) { za[j] = MFMA(a, pz[j][k], za[j]); ra[j] = MFMA(a, pr[j][k], ra[j]); }
        }
#pragma unroll
        for (int k = 0; k < 2; ++k) {
          bf16x8 a = *(const bf16x8*)(xb + (k << 9) + (lane << 3));
#pragma unroll
          for (int j = 0; j < 2; ++j) {
            bf16x8 bz_ = *(const bf16x8*)(xw + ((((2 * wave + j) << 1) | k) << 9) + (lane << 3));
            bf16x8 br_ = *(const bf16x8*)(xw + ((((16 + 2 * wave + j) << 1) | k) << 9) + (lane << 3));
            za[j] = MFMA(a, bz_, za[j]); ra[j] = MFMA(a, br_, ra[j]);
          }
        }
        float zg[2][4];
#pragma unroll
        for (int j = 0; j < 2; ++j)
#pragma unroll
          for (int i = 0; i < 4; ++i) {
            zg[j][i] = sigm(za[j][i]);
            rh0f[dloc[j] + i * 8] = f2bf(sigm(ra[j][i]) * h0s[j][i]);
          }
        lbar();   // MID barrier: lgkm-only (R20)

        f32x4 ca[2];
#pragma unroll
        for (int j = 0; j < 2; ++j) ca[j] = {bcc[j],bcc[j],bcc[j],bcc[j]};
#pragma unroll
        for (int k = 0; k < 6; ++k) {
          bf16x8 a = *(const bf16x8*)(rh0f + (k << 9) + (lane << 3));
#pragma unroll
          for (int j = 0; j < 2; ++j) ca[j] = MFMA(a, pc[j][k], ca[j]);
        }
#pragma unroll
        for (int kk = 0; kk < 2; ++kk) {   // c kt 6,7 weights from LDS
          bf16x8 a = *(const bf16x8*)(rh0f + ((6 + kk) << 9) + (lane << 3));
#pragma unroll
          for (int j = 0; j < 2; ++j) {
            bf16x8 bc_ = *(const bf16x8*)(cw0 + ((((2 * wave + j) << 1) | kk) << 9) + (lane << 3));
            ca[j] = MFMA(a, bc_, ca[j]);
          }
        }
#pragma unroll
        for (int k = 0; k < 2; ++k) {
          bf16x8 a = *(const bf16x8*)(xb + (k << 9) + (lane << 3));
#pragma unroll
          for (int j = 0; j < 2; ++j) {
            bf16x8 bc_ = *(const bf16x8*)(xw + 32768 + ((((2 * wave + j) << 1) | k) << 9) + (lane << 3));
            ca[j] = MFMA(a, bc_, ca[j]);
          }
        }
#pragma unroll
        for (int j = 0; j < 2; ++j)
#pragma unroll
          for (int i = 0; i < 4; ++i) {
            float ht = tanh_(ca[j][i]);
            float hn = h0s[j][i] + zg[j][i] * (ht - h0s[j][i]);
            h0s[j][i] = hn;
            h0f[dloc[j] + i * 8] = f2bf(hn);
          }
        if (havex) {
          unsigned short* xb1 = xf + (((t + 1) & 1) << 10);
          xb1[xbase] = f2bf(sanit(xn.x)); xb1[xbase + 1] = f2bf(sanit(xn.y));
          xb1[xbase + 2] = f2bf(sanit(xn.z)); xb1[xbase + 3] = f2bf(sanit(xn.w));
        }
        __syncthreads();   // END barrier: drains the step's ring stores + x load
      }
      {  // final frame of the chunk
        u32x4 fv = *(const u32x4*)((const char*)h0f + 16 * tid);
        st16((char*)(slot + 7 * 4096) + 16 * tid, fv);
      }
      publish(ctr + 0, ch + 1, tid);
    }
  } else if (stage == 1) {
    // ============ Stage B: layer1 h0-contribution (byte-identical to R20) ============
    unsigned short* cwB = lds;             // Wc1 h0-part kt 14,15: 32 tiles
    for (int u = tid; u < 2048; u += 512) {
      int flat = u << 3, ti = flat >> 9, q = flat & 511;
      int srct = 992 + (ti >> 1) * 16 + 14 + (ti & 1);
      *(uint4*)(cwB + flat) = *(const uint4*)(wsw + srct * 512 + q);
    }
    __syncthreads();

    bf16x8 p1[2][8], p2[2][8], p3[2][6];  // z,r -> AGPR; Wc1 kt 8..13 -> AGPR
#pragma unroll
    for (int j = 0; j < 2; ++j) {
      const int nt = 2 * wave + j;
#pragma unroll
      for (int k = 0; k < 8; ++k) {
        p1[j][k] = wsv[(480 + nt * 16 + 8 + k) * 64 + lane];
        p2[j][k] = wsv[(480 + (16 + nt) * 16 + 8 + k) * 64 + lane];
      }
#pragma unroll
      for (int k = 0; k < 6; ++k)
        p3[j][k] = wsv[(992 + nt * 16 + 8 + k) * 64 + lane];
    }
#pragma unroll
    for (int j = 0; j < 2; ++j) {
#pragma unroll
      for (int k = 0; k < 8; ++k)
        asm volatile("" : "+a"(p1[j][k]), "+a"(p2[j][k]));
#pragma unroll
      for (int k = 0; k < 6; ++k)
        asm volatile("" : "+a"(p3[j][k]));
    }
    float b1[2], b2[2], b3[2];
#pragma unroll
    for (int j = 0; j < 2; ++j) {
      const int col = 32 * wave + 16 * j + l15;
      b1[j] = bz1[col]; b2[j] = bz1[256 + col]; b3[j] = bc1[col];
    }
    for (int ch = 0; ch < NCH; ++ch) {
      waitge(ctr + 0, ch + 1, tid);                       // A published chunk
      if (ch >= DEPTH) waitge(ctr + 3, ch - (DEPTH - 1), tid);  // C freed p-slot
      const unsigned short* hslot = ringh + (ch & (DEPTH - 1)) * (CH * 4096);
      unsigned short* pslot = ringp + (ch & (DEPTH - 1)) * (CH * 12288);
      for (int s = 0; s < CH; ++s) {
        u32x4 cf[8];
        ld_frame8(hslot + s * 4096, lane, cf);   // 8 loads in flight, 1 waitcnt
        f32x4 za[2] = {{0,0,0,0},{0,0,0,0}};
        f32x4 ra[2] = {{0,0,0,0},{0,0,0,0}};
        f32x4 ca[2] = {{0,0,0,0},{0,0,0,0}};
#pragma unroll
        for (int k = 0; k < 8; ++k) {
          UB ub; ub.q = cf[k];
          bf16x8 a = ub.v;
#pragma unroll
          for (int j = 0; j < 2; ++j) {
            za[j] = MFMA(a, p1[j][k], za[j]);
            ra[j] = MFMA(a, p2[j][k], ra[j]);
            if (k < 6) ca[j] = MFMA(a, p3[j][k], ca[j]);
          }
        }
#pragma unroll
        for (int kk = 0; kk < 2; ++kk) {   // c kt 14,15 weights from LDS
          UB ub; ub.q = cf[6 + kk];
          bf16x8 a = ub.v;
#pragma unroll
          for (int j = 0; j < 2; ++j) {
            bf16x8 bc_ = *(const bf16x8*)(cwB + ((((2 * wave + j) << 1) | kk) << 9) + (lane << 3));
            ca[j] = MFMA(a, bc_, ca[j]);
          }
        }
        u64* pf = (u64*)(pslot + s * 12288);
#pragma unroll
        for (int j = 0; j < 2; ++j) {
          ushort4 vz, vr, vc;
          vz.x = f2bf(za[j][0] + b1[j]); vz.y = f2bf(za[j][1] + b1[j]);
          vz.z = f2bf(za[j][2] + b1[j]); vz.w = f2bf(za[j][3] + b1[j]);
          vr.x = f2bf(ra[j][0] + b2[j]); vr.y = f2bf(ra[j][1] + b2[j]);
          vr.z = f2bf(ra[j][2] + b2[j]); vr.w = f2bf(ra[j][3] + b2[j]);
          vc.x = f2bf(ca[j][0] + b3[j]); vc.y = f2bf(ca[j][1] + b3[j]);
          vc.z = f2bf(ca[j][2] + b3[j]); vc.w = f2bf(ca[j][3] + b3[j]);
          st8(pf + (2 * wave + j) * 64 + lane,      __builtin_bit_cast(u64, vz));
          st8(pf + (16 + 2 * wave + j) * 64 + lane, __builtin_bit_cast(u64, vr));
          st8(pf + (32 + 2 * wave + j) * 64 + lane, __builtin_bit_cast(u64, vc));
        }
      }
      publish(ctr + 1, ch + 1, tid);
      if (tid == 0)
        __hip_atomic_store(ctr + 2, ch + 1, __ATOMIC_RELAXED, __HIP_MEMORY_SCOPE_AGENT);
    }
  } else {
    // ======== Stage C: layer1 recurrence + LN, with cross-step prefetch ========
    unsigned short* h1f  = lds;
    unsigned short* rh1f = lds + 4096;
    unsigned short* cwC  = lds + 8192;     // Wc1 h1-part kt 6,7: 32 tiles
    for (int u = tid; u < 2048; u += 512) {
      int flat = u << 3, ti = flat >> 9, q = flat & 511;
      int srct = 992 + (ti >> 1) * 16 + 6 + (ti & 1);
      *(uint4*)(cwC + flat) = *(const uint4*)(wsw + srct * 512 + q);
    }
    bf16x8 q1[2][8], q2[2][8], q3[2][6];  // z,r h1-halves + c kt<6 -> AGPR
#pragma unroll
    for (int j = 0; j < 2; ++j) {
      const int nt = 2 * wave + j;
#pragma unroll
      for (int k = 0; k < 8; ++k) {
        q1[j][k] = wsv[(480 + nt * 16 + k) * 64 + lane];
        q2[j][k] = wsv[(480 + (16 + nt) * 16 + k) * 64 + lane];
      }
#pragma unroll
      for (int k = 0; k < 6; ++k)
        q3[j][k] = wsv[(992 + nt * 16 + k) * 64 + lane];
    }
#pragma unroll
    for (int j = 0; j < 2; ++j) {
#pragma unroll
      for (int k = 0; k < 8; ++k)
        asm volatile("" : "+a"(q1[j][k]), "+a"(q2[j][k]));
#pragma unroll
      for (int k = 0; k < 6; ++k)
        asm volatile("" : "+a"(q3[j][k]));
    }
    for (int i = tid; i < 4096; i += 512) h1f[i] = 0;
    int dloc[2];
#pragma unroll
    for (int j = 0; j < 2; ++j) dloc[j] = DLOC(32 * wave + 16 * j + l15);
    f32x4 h1s[2] = {{0,0,0,0},{0,0,0,0}};
    __syncthreads();

    // one GRU step: phase-1 (z,r + gates, rh1f), lgkm-only mid barrier,
    // phase-2 (c + h1 update, h1f), end __syncthreads (drains prefetch).
    auto cstep = [&](const u64* zq, const u64* rq, const u64* cq) {
      f32x4 za[2] = {{0,0,0,0},{0,0,0,0}};
      f32x4 ra[2] = {{0,0,0,0},{0,0,0,0}};
#pragma unroll
      for (int k = 0; k < 8; ++k) {
        bf16x8 a = *(const bf16x8*)(h1f + (k << 9) + (lane << 3));
#pragma unroll
        for (int j = 0; j < 2; ++j) { za[j] = MFMA(a, q1[j][k], za[j]); ra[j] = MFMA(a, q2[j][k], ra[j]); }
      }
      float zg[2][4];
#pragma unroll
      for (int j = 0; j < 2; ++j) {
        UB8 uz, ur; uz.q = zq[j]; ur.q = rq[j];
#pragma unroll
        for (int i = 0; i < 4; ++i) {
          zg[j][i] = sigm(za[j][i] + bf2f(((const unsigned short*)&uz.s)[i]));
          float r = sigm(ra[j][i] + bf2f(((const unsigned short*)&ur.s)[i]));
          rh1f[dloc[j] + i * 8] = f2bf(r * h1s[j][i]);
        }
      }
      lbar();   // mid: lgkm-only -- keeps the prefetch in flight

      f32x4 ca[2] = {{0,0,0,0},{0,0,0,0}};
#pragma unroll
      for (int k = 0; k < 6; ++k) {
        bf16x8 a = *(const bf16x8*)(rh1f + (k << 9) + (lane << 3));
#pragma unroll
        for (int j = 0; j < 2; ++j) ca[j] = MFMA(a, q3[j][k], ca[j]);
      }
#pragma unroll
      for (int kk = 0; kk < 2; ++kk) {   // c kt 6,7 weights from LDS
        bf16x8 a = *(const bf16x8*)(rh1f + ((6 + kk) << 9) + (lane << 3));
#pragma unroll
        for (int j = 0; j < 2; ++j) {
          bf16x8 bc_ = *(const bf16x8*)(cwC + ((((2 * wave + j) << 1) | kk) << 9) + (lane << 3));
          ca[j] = MFMA(a, bc_, ca[j]);
        }
      }
#pragma unroll
      for (int j = 0; j < 2; ++j) {
        UB8 uc; uc.q = cq[j];
#pragma unroll
        for (int i = 0; i < 4; ++i) {
          float ht = tanh_(ca[j][i] + bf2f(((const unsigned short*)&uc.s)[i]));
          float hn = h1s[j][i] + zg[j][i] * (ht - h1s[j][i]);
          h1s[j][i] = hn;
          h1f[dloc[j] + i * 8] = f2bf(hn);
        }
      }
      __syncthreads();   // end: drains the prefetch issued at step top
    };

    for (int ch = 0; ch < NCH; ++ch) {
      waitge(ctr + 1, ch + 1, tid);
      const unsigned short* pslot = ringp + (ch & (DEPTH - 1)) * (CH * 12288);
      u64 zqA[2], rqA[2], cqA[2], zqB[2], rqB[2], cqB[2];
      ld_part6(pslot, wave, lane, zqA, rqA, cqA);   // blocking, step 0 only
#pragma unroll
      for (int s2 = 0; s2 < 4; ++s2) {
        const int s = 2 * s2;
        // step s (A-buffers): issue s+1 prefetch at step top
        ld_part6_issue(pslot + (s + 1) * 12288, wave, lane, zqB, rqB, cqB);
        cstep(zqA, rqA, cqA);
        wait_tie6(zqB, rqB, cqB);   // free (end barrier drained); ties regs
        // step s+1 (B-buffers): issue s+2 prefetch (except last pair)
        if (s2 < 3) {
          ld_part6_issue(pslot + (s + 2) * 12288, wave, lane, zqA, rqA, cqA);
          cstep(zqB, rqB, cqB);
          wait_tie6(zqA, rqA, cqA);
        } else {
          cstep(zqB, rqB, cqB);
        }
      }
      publish(ctr + 3, ch + 1, tid);
    }

    // LayerNorm from fp32 h1 state via LDS staging (reuses bytes 0..16383)
    float* h1buf = (float*)lds;   // 16 x 256 fp32 = 16 KB
#pragma unroll
    for (int j = 0; j < 2; ++j)
#pragma unroll
      for (int i = 0; i < 4; ++i)
        h1buf[(quad * 4 + i) * 256 + 32 * wave + 16 * j + l15] = h1s[j][i];
    __syncthreads();

    if (tid < 256) {
      const int r = tid >> 4, cl = tid & 15;
      float v[16], s = 0.f, sq = 0.f;
#pragma unroll
      for (int jj = 0; jj < 16; ++jj) {
        v[jj] = h1buf[r * 256 + cl + (jj << 4)];
        s += v[jj]; sq += v[jj] * v[jj];
      }
#pragma unroll
      for (int off = 8; off > 0; off >>= 1) {   // 16-lane group reduce
        s  += __shfl_xor(s, off);
        sq += __shfl_xor(sq, off);
      }
      const float mean = s * (1.f / 256.f);
      const float var  = sq * (1.f / 256.f) - mean * mean;
      const float rstd = rsqrtf(var + 1e-5f);
      float* op = out + (size_t)(row0 + r) * 256;
#pragma unroll
      for (int jj = 0; jj < 16; ++jj) {
        const int c = cl + (jj << 4);
        op[c] = (v[jj] - mean) * rstd * gamma[c] + beta[c];
      }
    }
  }
}

extern "C" void kernel_launch(void* const* d_in, const int* in_sizes, int n_in,
                              void* d_out, int out_size, void* d_ws, size_t ws_size,
                              hipStream_t stream) {
  const float* x     = (const float*)d_in[0];
  const float* Wz0   = (const float*)d_in[1];
  const float* bz0   = (const float*)d_in[2];
  const float* Wc0   = (const float*)d_in[3];
  const float* bc0   = (const float*)d_in[4];
  const float* Wz1   = (const float*)d_in[5];
  const float* bz1   = (const float*)d_in[6];
  const float* Wc1   = (const float*)d_in[7];
  const float* bc1   = (const float*)d_in[8];
  const float* gamma = (const float*)d_in[9];
  const float* beta  = (const float*)d_in[10];
  unsigned short* ws = (unsigned short*)d_ws;
  float* out = (float*)d_out;

  hipMemsetAsync((char*)d_ws + CTRB, 0, 1024, stream);
  hipLaunchKernelGGL(prep_weights, dim3(2496), dim3(256), 0, stream, Wz0, Wc0, Wz1, Wc1, ws);
  hipLaunchKernelGGL(gru_pipe, dim3(48), dim3(512), 0, stream,
                     x, bz0, bc0, bz1, bc1, gamma, beta, ws, ws, out);
}

// Round 12
// 2295.917 us; speedup vs baseline: 1.2342x; 1.2342x over previous
//
#include <hip/hip_runtime.h>

// TimeframeEncoder R24: R20 base + C within-SEGMENT load hide (one variable).
// R22/R23 (prefetch across barriers) regressed 23% with the 4th instance of
// the WRITE_SIZE signature (+16MB from a LOAD-timing change) => law: coherent
// ring ops in flight ACROSS a barrier perturb MALL store-combining globally.
// This round: the untested safe variant. C only: issue the 6 partial loads,
// run the 16 z/r MFMAs (depend only on h1f LDS + AGPR weights), THEN wait
// vmcnt(0) (sched_barrier-pinned both sides, rule #18). Nothing outstanding
// at ANY barrier -- drain semantics byte-identical to R20. Hides ~200-300cy
// of the coherent round trip under the MFMA cluster. A/B byte-identical.

#define SEQL 512
#define CH 8
#define NCH 64
#define DEPTH 4

#define RB0  1310720u                   // rings base (weights end 1,277,952)
#define GSTR 1048576u                   // per group: 4x64KB h0 + 4x192KB partials
#define CTRB (RB0 + 16u * GSTR)         // counters: 16 groups x 64 B

typedef __bf16 bf16x8 __attribute__((ext_vector_type(8)));
typedef float f32x4 __attribute__((ext_vector_type(4)));
typedef unsigned int u32x4 __attribute__((ext_vector_type(4)));
typedef unsigned long long u64;

__device__ __forceinline__ unsigned short f2bf(float f) {
  unsigned int u = __builtin_bit_cast(unsigned int, f);
  u += 0x7fffu + ((u >> 16) & 1u);
  return (unsigned short)(u >> 16);
}
__device__ __forceinline__ float bf2f(unsigned short u) {
  unsigned int v = ((unsigned int)u) << 16;
  return __builtin_bit_cast(float, v);
}
__device__ __forceinline__ float sigm(float x) { return 1.0f / (1.0f + __expf(-x)); }
__device__ __forceinline__ float tanh_(float x) { return 1.0f - 2.0f / (__expf(2.0f * x) + 1.0f); }
__device__ __forceinline__ float sanit(float v) {
  if (!(v == v)) return 0.f;
  if (isinf(v)) return v > 0.f ? 10.f : -10.f;
  return v;
}

// agent-coherent stores (fire-and-forget; proven correct R8/R11)
__device__ __forceinline__ void st8(u64* p, u64 v) {
  __hip_atomic_store(p, v, __ATOMIC_RELAXED, __HIP_MEMORY_SCOPE_AGENT);
}
// 16B device-coherent store (same sc0 sc1 encoding, wider; R16/R20-verified)
__device__ __forceinline__ void st16(void* p, u32x4 v) {
  asm volatile("global_store_dwordx4 %0, %1, off sc0 sc1" :: "v"(p), "v"(v) : "memory");
}

// lgkm-only barrier: orders LDS without draining outstanding global stores.
__device__ __forceinline__ void lbar() {
  asm volatile("s_waitcnt lgkmcnt(0)" ::: "memory");
  __builtin_amdgcn_sched_barrier(0);
  __builtin_amdgcn_s_barrier();
  __builtin_amdgcn_sched_barrier(0);
}

// ---- batched device-coherent load blocks ----
__device__ __forceinline__ void ld_frame8(const unsigned short* base, int lane, u32x4* c) {
  const char* p0 = (const char*)base + lane * 16;
  const char* p4 = p0 + 4096;
  asm volatile(
      "global_load_dwordx4 %0, %8, off sc0 sc1\n\t"
      "global_load_dwordx4 %1, %8, off offset:1024 sc0 sc1\n\t"
      "global_load_dwordx4 %2, %8, off offset:2048 sc0 sc1\n\t"
      "global_load_dwordx4 %3, %8, off offset:3072 sc0 sc1\n\t"
      "global_load_dwordx4 %4, %9, off sc0 sc1\n\t"
      "global_load_dwordx4 %5, %9, off offset:1024 sc0 sc1\n\t"
      "global_load_dwordx4 %6, %9, off offset:2048 sc0 sc1\n\t"
      "global_load_dwordx4 %7, %9, off offset:3072 sc0 sc1\n\t"
      "s_waitcnt vmcnt(0)"
      : "=&v"(c[0]), "=&v"(c[1]), "=&v"(c[2]), "=&v"(c[3]),
        "=&v"(c[4]), "=&v"(c[5]), "=&v"(c[6]), "=&v"(c[7])
      : "v"(p0), "v"(p4)
      : "memory");
}
// C: issue-only (wait comes after the z/r MFMA cluster).
__device__ __forceinline__ void ld_part6_issue(const unsigned short* pf, int wave, int lane,
                                               u64* z, u64* r, u64* c) {
  const char* p0 = (const char*)pf + ((2 * wave) * 64 + lane) * 8;
  const char* p1 = p0 + 8192;
  const char* p2 = p0 + 16384;
  asm volatile(
      "global_load_dwordx2 %0, %6, off sc0 sc1\n\t"
      "global_load_dwordx2 %1, %6, off offset:512 sc0 sc1\n\t"
      "global_load_dwordx2 %2, %7, off sc0 sc1\n\t"
      "global_load_dwordx2 %3, %7, off offset:512 sc0 sc1\n\t"
      "global_load_dwordx2 %4, %8, off sc0 sc1\n\t"
      "global_load_dwordx2 %5, %8, off offset:512 sc0 sc1"
      : "=&v"(z[0]), "=&v"(z[1]), "=&v"(r[0]), "=&v"(r[1]),
        "=&v"(c[0]), "=&v"(c[1])
      : "v"(p0), "v"(p1), "v"(p2)
      : "memory");
}
// full drain + reg ties, sched_barrier-pinned on BOTH sides so the z/r MFMA
// cluster stays above and the gates stay below (rule #18).
__device__ __forceinline__ void wait_all6(u64* z, u64* r, u64* c) {
  __builtin_amdgcn_sched_barrier(0);
  asm volatile("s_waitcnt vmcnt(0)"
      : "+v"(z[0]), "+v"(z[1]), "+v"(r[0]), "+v"(r[1]), "+v"(c[0]), "+v"(c[1])
      :: "memory");
  __builtin_amdgcn_sched_barrier(0);
}

// Weight prep (layout verified R1-R11): bf16 B-fragments, tile = 512 ushort,
// lane L holds B[k=(L>>4)*8+j][n=L&15]. Wz0p tiles [0,320) (nt<32,kt<10);
// Wc0p base 320 (nt<16,kt<10); Wz1p base 480 (nt<32,kt<16); Wc1p base 992.
__global__ __launch_bounds__(256) void prep_weights(
    const float* __restrict__ Wz0, const float* __restrict__ Wc0,
    const float* __restrict__ Wz1, const float* __restrict__ Wc1,
    unsigned short* __restrict__ ws) {
  int idx = blockIdx.x * 256 + threadIdx.x;  // 638976 threads
  const float* W;
  int stride, KT, base;
  if (idx < 163840)      { W = Wz0; stride = 768; KT = 10; base = 0; }
  else if (idx < 245760) { W = Wc0; stride = 256; KT = 10; base = 163840; idx -= 163840; }
  else if (idx < 507904) { W = Wz1; stride = 768; KT = 16; base = 245760; idx -= 245760; }
  else                   { W = Wc1; stride = 256; KT = 16; base = 507904; idx -= 507904; }
  int tile = idx >> 9;
  int t = idx & 511;
  int nt = tile / KT;
  int kt = tile - nt * KT;
  int n15 = t & 15;
  int klocal = t >> 4;
  int k = (kt << 5) + klocal;
  int n = (nt << 4) + n15;
  int lane = ((klocal >> 3) << 4) | n15;
  int j = klocal & 7;
  ws[base + (tile << 9) + (lane << 3) + j] = f2bf(W[k * stride + n]);
}

__device__ __forceinline__ void waitge(int* p, int v, int tid) {
  __syncthreads();
  if (tid == 0) {
    long it = 0;
    while (__hip_atomic_load(p, __ATOMIC_RELAXED, __HIP_MEMORY_SCOPE_AGENT) < v) {
      __builtin_amdgcn_s_sleep(1);
      if (++it > (1L << 24)) break;  // valve against true deadlock
    }
  }
  __syncthreads();
}
__device__ __forceinline__ void publish(int* p, int v, int tid) {
  asm volatile("s_waitcnt vmcnt(0)" ::: "memory");
  __syncthreads();
  if (tid == 0) __hip_atomic_store(p, v, __ATOMIC_RELAXED, __HIP_MEMORY_SCOPE_AGENT);
}

#define DLOC(c) ((((c) >> 5) << 9) + (((((c) >> 3) & 3) << 4) + (quad << 2)) * 8 + ((c) & 7))
#define MFMA(a, b, c) __builtin_amdgcn_mfma_f32_16x16x32_bf16((a), (b), (c), 0, 0, 0)

union UB  { u32x4 q; bf16x8 v; };
union UB8 { u64 q; ushort4 s; };

__global__ __launch_bounds__(512, 2) void gru_pipe(
    const float* __restrict__ x,
    const float* __restrict__ bz0, const float* __restrict__ bc0,
    const float* __restrict__ bz1, const float* __restrict__ bc1,
    const float* __restrict__ gamma, const float* __restrict__ beta,
    const unsigned short* __restrict__ wsw,
    unsigned short* __restrict__ gws,
    float* __restrict__ out) {
  __shared__ __align__(16) unsigned short lds[75776];  // 148 KB (stage A max)
  const int tid  = threadIdx.x;
  const int wave = tid >> 6;   // 0..7
  const int lane = tid & 63;
  const int l15  = lane & 15;
  const int quad = lane >> 4;
  const int stage = blockIdx.x >> 4;
  const int g     = blockIdx.x & 15;
  const int row0  = g << 4;

  const bf16x8* __restrict__ wsv = (const bf16x8*)wsw;
  unsigned short* ringh = gws + (RB0 >> 1) + (size_t)g * (GSTR >> 1);  // 4 x 32768 ushort
  unsigned short* ringp = ringh + 131072;                              // 4 x 98304 ushort
  int* ctr = (int*)((char*)gws + CTRB) + g * 16;  // [0]A_pub [1]B_pub [2]B_ack [3]C_ack

  if (stage == 0) {
    // ================= Stage A: layer0 (byte-identical to R20) =================
    unsigned short* h0f  = lds;            // 8 kt A-frag of h0
    unsigned short* rh0f = lds + 4096;
    unsigned short* xf   = lds + 8192;     // 2 bufs x 2 kt
    unsigned short* xw   = lds + 10240;    // x-part B tiles: 96 x 512 ushort
    unsigned short* cw0  = lds + 59392;    // Wc0 h-part kt 6,7: 32 tiles (32 KB)
    for (int u = tid; u < 6144; u += 512) {
      int flat = u << 3, ti = flat >> 9, q = flat & 511, srct;
      if (ti < 64) srct = (ti >> 1) * 10 + 8 + (ti & 1);
      else         srct = 320 + ((ti - 64) >> 1) * 10 + 8 + (ti & 1);
      *(uint4*)(xw + flat) = *(const uint4*)(wsw + srct * 512 + q);
    }
    for (int u = tid; u < 2048; u += 512) {  // cw0: tile ti = nt*2 + kk, kk = k-6
      int flat = u << 3, ti = flat >> 9, q = flat & 511;
      int srct = 320 + (ti >> 1) * 10 + 6 + (ti & 1);
      *(uint4*)(cw0 + flat) = *(const uint4*)(wsw + srct * 512 + q);
    }
    for (int i = tid; i < 4096; i += 512) h0f[i] = 0;

    // per-wave (j<2): z,r h-part -> AGPR (32 tiles = 128); c kt<6 -> AGPR (48)
    bf16x8 pz[2][8], pr[2][8], pc[2][6];
#pragma unroll
    for (int j = 0; j < 2; ++j) {
      const int zt = 2 * wave + j;
#pragma unroll
      for (int k = 0; k < 8; ++k) {
        pz[j][k] = wsv[(zt * 10 + k) * 64 + lane];
        pr[j][k] = wsv[((16 + zt) * 10 + k) * 64 + lane];
      }
#pragma unroll
      for (int k = 0; k < 6; ++k)
        pc[j][k] = wsv[(320 + zt * 10 + k) * 64 + lane];
    }
#pragma unroll
    for (int j = 0; j < 2; ++j) {
#pragma unroll
      for (int k = 0; k < 8; ++k)
        asm volatile("" : "+a"(pz[j][k]), "+a"(pr[j][k]));
#pragma unroll
      for (int k = 0; k < 6; ++k)
        asm volatile("" : "+a"(pc[j][k]));
    }

    float bzz[2], bzr[2], bcc[2];
    int dloc[2];
#pragma unroll
    for (int j = 0; j < 2; ++j) {
      const int col = 32 * wave + 16 * j + l15;
      bzz[j] = bz0[col]; bzr[j] = bz0[256 + col]; bcc[j] = bc0[col];
      dloc[j] = DLOC(col);
    }
    f32x4 h0s[2] = {{0,0,0,0},{0,0,0,0}};

    const int xrow = (tid >> 4) & 15, c4 = (tid & 15) << 2;
    const float* xp = x + (size_t)(row0 + xrow) * (SEQL * 64) + c4;
    const int xbase = ((c4 >> 5) << 9) + ((((c4 >> 3) & 3) << 4) + xrow) * 8 + (c4 & 7);
    if (tid < 256) {
      float4 xv = *(const float4*)xp;
      xf[xbase] = f2bf(sanit(xv.x)); xf[xbase + 1] = f2bf(sanit(xv.y));
      xf[xbase + 2] = f2bf(sanit(xv.z)); xf[xbase + 3] = f2bf(sanit(xv.w));
    }
    __syncthreads();

    for (int ch = 0; ch < NCH; ++ch) {
      if (ch >= DEPTH) waitge(ctr + 2, ch - (DEPTH - 1), tid);   // B freed this slot
      unsigned short* slot = ringh + (ch & (DEPTH - 1)) * (CH * 4096);
      for (int s = 0; s < CH; ++s) {
        const int t = (ch << 3) + s;
        if (s > 0) {  // prev step's h0 frame: one 16B coherent store/thread
          u32x4 fv = *(const u32x4*)((const char*)h0f + 16 * tid);
          st16((char*)(slot + (s - 1) * 4096) + 16 * tid, fv);
        }
        const unsigned short* xb = xf + ((t & 1) << 10);
        const bool havex = (t + 1 < SEQL) && (tid < 256);
        float4 xn;
        if (havex) xn = *(const float4*)(xp + (t + 1) * 64);

        f32x4 za[2], ra[2];
#pragma unroll
        for (int j = 0; j < 2; ++j) { za[j] = {bzz[j],bzz[j],bzz[j],bzz[j]}; ra[j] = {bzr[j],bzr[j],bzr[j],bzr[j]}; }
#pragma unroll
        for (int k = 0; k < 8; ++k) {
          bf16x8 a = *(const bf16x8*)(h0f + (k << 9) + (lane << 3));
#pragma unroll
          for (int j = 0; j < 2; ++j) { za[j] = MFMA(a, pz[j][k], za[j]); ra[j] = MFMA(a, pr[j][k], ra[j]); }
        }
#pragma unroll
        for (int k = 0; k < 2; ++k) {
          bf16x8 a = *(const bf16x8*)(xb + (k << 9) + (lane << 3));
#pragma unroll
          for (int j = 0; j < 2; ++j) {
            bf16x8 bz_ = *(const bf16x8*)(xw + ((((2 * wave + j) << 1) | k) << 9) + (lane << 3));
            bf16x8 br_ = *(const bf16x8*)(xw + ((((16 + 2 * wave + j) << 1) | k) << 9) + (lane << 3));
            za[j] = MFMA(a, bz_, za[j]); ra[j] = MFMA(a, br_, ra[j]);
          }
        }
        float zg[2][4];
#pragma unroll
        for (int j = 0; j < 2; ++j)
#pragma unroll
          for (int i = 0; i < 4; ++i) {
            zg[j][i] = sigm(za[j][i]);
            rh0f[dloc[j] + i * 8] = f2bf(sigm(ra[j][i]) * h0s[j][i]);
          }
        lbar();   // MID barrier: lgkm-only (R20)

        f32x4 ca[2];
#pragma unroll
        for (int j = 0; j < 2; ++j) ca[j] = {bcc[j],bcc[j],bcc[j],bcc[j]};
#pragma unroll
        for (int k = 0; k < 6; ++k) {
          bf16x8 a = *(const bf16x8*)(rh0f + (k << 9) + (lane << 3));
#pragma unroll
          for (int j = 0; j < 2; ++j) ca[j] = MFMA(a, pc[j][k], ca[j]);
        }
#pragma unroll
        for (int kk = 0; kk < 2; ++kk) {   // c kt 6,7 weights from LDS
          bf16x8 a = *(const bf16x8*)(rh0f + ((6 + kk) << 9) + (lane << 3));
#pragma unroll
          for (int j = 0; j < 2; ++j) {
            bf16x8 bc_ = *(const bf16x8*)(cw0 + ((((2 * wave + j) << 1) | kk) << 9) + (lane << 3));
            ca[j] = MFMA(a, bc_, ca[j]);
          }
        }
#pragma unroll
        for (int k = 0; k < 2; ++k) {
          bf16x8 a = *(const bf16x8*)(xb + (k << 9) + (lane << 3));
#pragma unroll
          for (int j = 0; j < 2; ++j) {
            bf16x8 bc_ = *(const bf16x8*)(xw + 32768 + ((((2 * wave + j) << 1) | k) << 9) + (lane << 3));
            ca[j] = MFMA(a, bc_, ca[j]);
          }
        }
#pragma unroll
        for (int j = 0; j < 2; ++j)
#pragma unroll
          for (int i = 0; i < 4; ++i) {
            float ht = tanh_(ca[j][i]);
            float hn = h0s[j][i] + zg[j][i] * (ht - h0s[j][i]);
            h0s[j][i] = hn;
            h0f[dloc[j] + i * 8] = f2bf(hn);
          }
        if (havex) {
          unsigned short* xb1 = xf + (((t + 1) & 1) << 10);
          xb1[xbase] = f2bf(sanit(xn.x)); xb1[xbase + 1] = f2bf(sanit(xn.y));
          xb1[xbase + 2] = f2bf(sanit(xn.z)); xb1[xbase + 3] = f2bf(sanit(xn.w));
        }
        __syncthreads();   // END barrier: drains the step's ring stores + x load
      }
      {  // final frame of the chunk
        u32x4 fv = *(const u32x4*)((const char*)h0f + 16 * tid);
        st16((char*)(slot + 7 * 4096) + 16 * tid, fv);
      }
      publish(ctr + 0, ch + 1, tid);
    }
  } else if (stage == 1) {
    // ============ Stage B: layer1 h0-contribution (byte-identical to R20) ============
    unsigned short* cwB = lds;             // Wc1 h0-part kt 14,15: 32 tiles
    for (int u = tid; u < 2048; u += 512) {
      int flat = u << 3, ti = flat >> 9, q = flat & 511;
      int srct = 992 + (ti >> 1) * 16 + 14 + (ti & 1);
      *(uint4*)(cwB + flat) = *(const uint4*)(wsw + srct * 512 + q);
    }
    __syncthreads();

    bf16x8 p1[2][8], p2[2][8], p3[2][6];  // z,r -> AGPR; Wc1 kt 8..13 -> AGPR
#pragma unroll
    for (int j = 0; j < 2; ++j) {
      const int nt = 2 * wave + j;
#pragma unroll
      for (int k = 0; k < 8; ++k) {
        p1[j][k] = wsv[(480 + nt * 16 + 8 + k) * 64 + lane];
        p2[j][k] = wsv[(480 + (16 + nt) * 16 + 8 + k) * 64 + lane];
      }
#pragma unroll
      for (int k = 0; k < 6; ++k)
        p3[j][k] = wsv[(992 + nt * 16 + 8 + k) * 64 + lane];
    }
#pragma unroll
    for (int j = 0; j < 2; ++j) {
#pragma unroll
      for (int k = 0; k < 8; ++k)
        asm volatile("" : "+a"(p1[j][k]), "+a"(p2[j][k]));
#pragma unroll
      for (int k = 0; k < 6; ++k)
        asm volatile("" : "+a"(p3[j][k]));
    }
    float b1[2], b2[2], b3[2];
#pragma unroll
    for (int j = 0; j < 2; ++j) {
      const int col = 32 * wave + 16 * j + l15;
      b1[j] = bz1[col]; b2[j] = bz1[256 + col]; b3[j] = bc1[col];
    }
    for (int ch = 0; ch < NCH; ++ch) {
      waitge(ctr + 0, ch + 1, tid);                       // A published chunk
      if (ch >= DEPTH) waitge(ctr + 3, ch - (DEPTH - 1), tid);  // C freed p-slot
      const unsigned short* hslot = ringh + (ch & (DEPTH - 1)) * (CH * 4096);
      unsigned short* pslot = ringp + (ch & (DEPTH - 1)) * (CH * 12288);
      for (int s = 0; s < CH; ++s) {
        u32x4 cf[8];
        ld_frame8(hslot + s * 4096, lane, cf);   // 8 loads in flight, 1 waitcnt
        f32x4 za[2] = {{0,0,0,0},{0,0,0,0}};
        f32x4 ra[2] = {{0,0,0,0},{0,0,0,0}};
        f32x4 ca[2] = {{0,0,0,0},{0,0,0,0}};
#pragma unroll
        for (int k = 0; k < 8; ++k) {
          UB ub; ub.q = cf[k];
          bf16x8 a = ub.v;
#pragma unroll
          for (int j = 0; j < 2; ++j) {
            za[j] = MFMA(a, p1[j][k], za[j]);
            ra[j] = MFMA(a, p2[j][k], ra[j]);
            if (k < 6) ca[j] = MFMA(a, p3[j][k], ca[j]);
          }
        }
#pragma unroll
        for (int kk = 0; kk < 2; ++kk) {   // c kt 14,15 weights from LDS
          UB ub; ub.q = cf[6 + kk];
          bf16x8 a = ub.v;
#pragma unroll
          for (int j = 0; j < 2; ++j) {
            bf16x8 bc_ = *(const bf16x8*)(cwB + ((((2 * wave + j) << 1) | kk) << 9) + (lane << 3));
            ca[j] = MFMA(a, bc_, ca[j]);
          }
        }
        u64* pf = (u64*)(pslot + s * 12288);
#pragma unroll
        for (int j = 0; j < 2; ++j) {
          ushort4 vz, vr, vc;
          vz.x = f2bf(za[j][0] + b1[j]); vz.y = f2bf(za[j][1] + b1[j]);
          vz.z = f2bf(za[j][2] + b1[j]); vz.w = f2bf(za[j][3] + b1[j]);
          vr.x = f2bf(ra[j][0] + b2[j]); vr.y = f2bf(ra[j][1] + b2[j]);
          vr.z = f2bf(ra[j][2] + b2[j]); vr.w = f2bf(ra[j][3] + b2[j]);
          vc.x = f2bf(ca[j][0] + b3[j]); vc.y = f2bf(ca[j][1] + b3[j]);
          vc.z = f2bf(ca[j][2] + b3[j]); vc.w = f2bf(ca[j][3] + b3[j]);
          st8(pf + (2 * wave + j) * 64 + lane,      __builtin_bit_cast(u64, vz));
          st8(pf + (16 + 2 * wave + j) * 64 + lane, __builtin_bit_cast(u64, vr));
          st8(pf + (32 + 2 * wave + j) * 64 + lane, __builtin_bit_cast(u64, vc));
        }
      }
      publish(ctr + 1, ch + 1, tid);
      if (tid == 0)
        __hip_atomic_store(ctr + 2, ch + 1, __ATOMIC_RELAXED, __HIP_MEMORY_SCOPE_AGENT);
    }
  } else {
    // ==== Stage C: layer1 recurrence + LN (R20 + within-segment load hide) ====
    unsigned short* h1f  = lds;
    unsigned short* rh1f = lds + 4096;
    unsigned short* cwC  = lds + 8192;     // Wc1 h1-part kt 6,7: 32 tiles
    for (int u = tid; u < 2048; u += 512) {
      int flat = u << 3, ti = flat >> 9, q = flat & 511;
      int srct = 992 + (ti >> 1) * 16 + 6 + (ti & 1);
      *(uint4*)(cwC + flat) = *(const uint4*)(wsw + srct * 512 + q);
    }
    bf16x8 q1[2][8], q2[2][8], q3[2][6];  // z,r h1-halves + c kt<6 -> AGPR
#pragma unroll
    for (int j = 0; j < 2; ++j) {
      const int nt = 2 * wave + j;
#pragma unroll
      for (int k = 0; k < 8; ++k) {
        q1[j][k] = wsv[(480 + nt * 16 + k) * 64 + lane];
        q2[j][k] = wsv[(480 + (16 + nt) * 16 + k) * 64 + lane];
      }
#pragma unroll
      for (int k = 0; k < 6; ++k)
        q3[j][k] = wsv[(992 + nt * 16 + k) * 64 + lane];
    }
#pragma unroll
    for (int j = 0; j < 2; ++j) {
#pragma unroll
      for (int k = 0; k < 8; ++k)
        asm volatile("" : "+a"(q1[j][k]), "+a"(q2[j][k]));
#pragma unroll
      for (int k = 0; k < 6; ++k)
        asm volatile("" : "+a"(q3[j][k]));
    }
    for (int i = tid; i < 4096; i += 512) h1f[i] = 0;
    int dloc[2];
#pragma unroll
    for (int j = 0; j < 2; ++j) dloc[j] = DLOC(32 * wave + 16 * j + l15);
    f32x4 h1s[2] = {{0,0,0,0},{0,0,0,0}};
    __syncthreads();

    for (int ch = 0; ch < NCH; ++ch) {
      waitge(ctr + 1, ch + 1, tid);
      const unsigned short* pslot = ringp + (ch & (DEPTH - 1)) * (CH * 12288);
      for (int s = 0; s < CH; ++s) {
        u64 zq[2], rq[2], cq[2];
        // issue the 6 coherent loads; wait AFTER the z/r MFMA cluster
        // (which depends only on h1f LDS + AGPR weights).
        ld_part6_issue(pslot + s * 12288, wave, lane, zq, rq, cq);
        f32x4 za[2] = {{0,0,0,0},{0,0,0,0}};
        f32x4 ra[2] = {{0,0,0,0},{0,0,0,0}};
#pragma unroll
        for (int k = 0; k < 8; ++k) {
          bf16x8 a = *(const bf16x8*)(h1f + (k << 9) + (lane << 3));
#pragma unroll
          for (int j = 0; j < 2; ++j) { za[j] = MFMA(a, q1[j][k], za[j]); ra[j] = MFMA(a, q2[j][k], ra[j]); }
        }
        wait_all6(zq, rq, cq);   // drain: nothing in flight at any barrier
        float zg[2][4];
#pragma unroll
        for (int j = 0; j < 2; ++j) {
          UB8 uz, ur; uz.q = zq[j]; ur.q = rq[j];
#pragma unroll
          for (int i = 0; i < 4; ++i) {
            zg[j][i] = sigm(za[j][i] + bf2f(((const unsigned short*)&uz.s)[i]));
            float r = sigm(ra[j][i] + bf2f(((const unsigned short*)&ur.s)[i]));
            rh1f[dloc[j] + i * 8] = f2bf(r * h1s[j][i]);
          }
        }
        __syncthreads();

        f32x4 ca[2] = {{0,0,0,0},{0,0,0,0}};
#pragma unroll
        for (int k = 0; k < 6; ++k) {
          bf16x8 a = *(const bf16x8*)(rh1f + (k << 9) + (lane << 3));
#pragma unroll
          for (int j = 0; j < 2; ++j) ca[j] = MFMA(a, q3[j][k], ca[j]);
        }
#pragma unroll
        for (int kk = 0; kk < 2; ++kk) {   // c kt 6,7 weights from LDS
          bf16x8 a = *(const bf16x8*)(rh1f + ((6 + kk) << 9) + (lane << 3));
#pragma unroll
          for (int j = 0; j < 2; ++j) {
            bf16x8 bc_ = *(const bf16x8*)(cwC + ((((2 * wave + j) << 1) | kk) << 9) + (lane << 3));
            ca[j] = MFMA(a, bc_, ca[j]);
          }
        }
#pragma unroll
        for (int j = 0; j < 2; ++j) {
          UB8 uc; uc.q = cq[j];
#pragma unroll
          for (int i = 0; i < 4; ++i) {
            float ht = tanh_(ca[j][i] + bf2f(((const unsigned short*)&uc.s)[i]));
            float hn = h1s[j][i] + zg[j][i] * (ht - h1s[j][i]);
            h1s[j][i] = hn;
            h1f[dloc[j] + i * 8] = f2bf(hn);
          }
        }
        __syncthreads();
      }
      publish(ctr + 3, ch + 1, tid);
    }

    // LayerNorm from fp32 h1 state via LDS staging (reuses bytes 0..16383)
    float* h1buf = (float*)lds;   // 16 x 256 fp32 = 16 KB
#pragma unroll
    for (int j = 0; j < 2; ++j)
#pragma unroll
      for (int i = 0; i < 4; ++i)
        h1buf[(quad * 4 + i) * 256 + 32 * wave + 16 * j + l15] = h1s[j][i];
    __syncthreads();

    if (tid < 256) {
      const int r = tid >> 4, cl = tid & 15;
      float v[16], s = 0.f, sq = 0.f;
#pragma unroll
      for (int jj = 0; jj < 16; ++jj) {
        v[jj] = h1buf[r * 256 + cl + (jj << 4)];
        s += v[jj]; sq += v[jj] * v[jj];
      }
#pragma unroll
      for (int off = 8; off > 0; off >>= 1) {   // 16-lane group reduce
        s  += __shfl_xor(s, off);
        sq += __shfl_xor(sq, off);
      }
      const float mean = s * (1.f / 256.f);
      const float var  = sq * (1.f / 256.f) - mean * mean;
      const float rstd = rsqrtf(var + 1e-5f);
      float* op = out + (size_t)(row0 + r) * 256;
#pragma unroll
      for (int jj = 0; jj < 16; ++jj) {
        const int c = cl + (jj << 4);
        op[c] = (v[jj] - mean) * rstd * gamma[c] + beta[c];
      }
    }
  }
}

extern "C" void kernel_launch(void* const* d_in, const int* in_sizes, int n_in,
                              void* d_out, int out_size, void* d_ws, size_t ws_size,
                              hipStream_t stream) {
  const float* x     = (const float*)d_in[0];
  const float* Wz0   = (const float*)d_in[1];
  const float* bz0   = (const float*)d_in[2];
  const float* Wc0   = (const float*)d_in[3];
  const float* bc0   = (const float*)d_in[4];
  const float* Wz1   = (const float*)d_in[5];
  const float* bz1   = (const float*)d_in[6];
  const float* Wc1   = (const float*)d_in[7];
  const float* bc1   = (const float*)d_in[8];
  const float* gamma = (const float*)d_in[9];
  const float* beta  = (const float*)d_in[10];
  unsigned short* ws = (unsigned short*)d_ws;
  float* out = (float*)d_out;

  hipMemsetAsync((char*)d_ws + CTRB, 0, 1024, stream);
  hipLaunchKernelGGL(prep_weights, dim3(2496), dim3(256), 0, stream, Wz0, Wc0, Wz1, Wc1, ws);
  hipLaunchKernelGGL(gru_pipe, dim3(48), dim3(512), 0, stream,
                     x, bz0, bc0, bz1, bc1, gamma, beta, ws, ws, out);
}